// Round 1
// baseline (213.824 us; speedup 1.0000x reference)
//
#include <hip/hip_runtime.h>
#include <math.h>

// Max pairwise L2 distance: max_{n,m} || L[n] - R[m] ||, L:[N,64], R:[M,64] fp32.
// Compute-bound fp32 GEMM-like kernel (no fp32 MFMA on CDNA4 -> vector ALU).
// 64x64 output tile per 256-thread block; D=64 staged once to transposed LDS.

constexpr int D  = 64;
constexpr int BM = 64;
constexpr int BN = 64;

__global__ void init_gmax_kernel(unsigned int* gmax) { *gmax = 0u; }

__global__ __launch_bounds__(256) void pairdist_max_kernel(
    const float* __restrict__ L, const float* __restrict__ R,
    unsigned int* __restrict__ gmax)
{
    __shared__ float lT[D][BM];   // lT[k][m] = L[bm+m][k], 16 KiB
    __shared__ float rT[D][BN];   // rT[k][n] = R[bn+n][k], 16 KiB
    __shared__ float lsq[BM];
    __shared__ float rsq[BN];
    __shared__ float wmax[4];

    const int tid = threadIdx.x;
    const int bm = blockIdx.x * BM;
    const int bn = blockIdx.y * BN;

    // Stage both tiles, transposed. 64 rows x 16 float4 = 1024 float4 per tile,
    // 4 per thread. Coalesced global loads; LDS write conflicts (16-way) happen
    // once per block and amortize over the 64 k-iterations of compute.
    #pragma unroll
    for (int i = 0; i < 4; ++i) {
        int idx = tid + i * 256;          // 0..1023
        int row = idx >> 4;
        int c4  = idx & 15;
        float4 lv = *reinterpret_cast<const float4*>(L + (size_t)(bm + row) * D + c4 * 4);
        float4 rv = *reinterpret_cast<const float4*>(R + (size_t)(bn + row) * D + c4 * 4);
        lT[c4*4+0][row] = lv.x; lT[c4*4+1][row] = lv.y;
        lT[c4*4+2][row] = lv.z; lT[c4*4+3][row] = lv.w;
        rT[c4*4+0][row] = rv.x; rT[c4*4+1][row] = rv.y;
        rT[c4*4+2][row] = rv.z; rT[c4*4+3][row] = rv.w;
    }
    __syncthreads();

    // Row norms from the staged tiles (column scan: lane m reads bank m%32,
    // 2 lanes/bank = free).
    if (tid < 64) {
        float s = 0.f;
        #pragma unroll
        for (int k = 0; k < D; ++k) { float v = lT[k][tid]; s += v * v; }
        lsq[tid] = s;
    } else if (tid < 128) {
        const int m = tid - 64;
        float s = 0.f;
        #pragma unroll
        for (int k = 0; k < D; ++k) { float v = rT[k][m]; s += v * v; }
        rsq[m] = s;
    }
    __syncthreads();

    // 16x16 thread layout, 4x4 micro-tile per thread.
    const int tx = tid & 15;
    const int ty = tid >> 4;
    const int m0 = ty * 4;
    const int n0 = tx * 4;

    float acc[4][4] = {};
    #pragma unroll
    for (int k = 0; k < D; ++k) {
        float4 a = *reinterpret_cast<const float4*>(&lT[k][m0]);
        float4 b = *reinterpret_cast<const float4*>(&rT[k][n0]);
        float av[4] = {a.x, a.y, a.z, a.w};
        float bv[4] = {b.x, b.y, b.z, b.w};
        #pragma unroll
        for (int i = 0; i < 4; ++i)
            #pragma unroll
            for (int j = 0; j < 4; ++j)
                acc[i][j] = fmaf(av[i], bv[j], acc[i][j]);
    }

    // sq_dist = lsq + rsq - 2*dot; track max (clamped >= 0).
    float lmax = 0.f;
    #pragma unroll
    for (int i = 0; i < 4; ++i) {
        const float ls = lsq[m0 + i];
        #pragma unroll
        for (int j = 0; j < 4; ++j) {
            float sq = ls + rsq[n0 + j] - 2.f * acc[i][j];
            lmax = fmaxf(lmax, sq);
        }
    }

    // Wave64 butterfly max-reduce, then cross-wave via LDS, one atomic/block.
    #pragma unroll
    for (int off = 32; off >= 1; off >>= 1)
        lmax = fmaxf(lmax, __shfl_xor(lmax, off, 64));
    if ((tid & 63) == 0) wmax[tid >> 6] = lmax;
    __syncthreads();
    if (tid == 0) {
        float bmax = fmaxf(fmaxf(wmax[0], wmax[1]), fmaxf(wmax[2], wmax[3]));
        bmax = fmaxf(bmax, 0.f);
        // Non-negative floats order identically to their uint bit patterns.
        atomicMax(gmax, __float_as_uint(bmax));
    }
}

__global__ void finalize_kernel(const unsigned int* __restrict__ gmax,
                                float* __restrict__ out)
{
    out[0] = sqrtf(__uint_as_float(*gmax));
}

extern "C" void kernel_launch(void* const* d_in, const int* in_sizes, int n_in,
                              void* d_out, int out_size, void* d_ws, size_t ws_size,
                              hipStream_t stream) {
    const float* L = (const float*)d_in[0];
    const float* R = (const float*)d_in[1];
    const int N = in_sizes[0] / D;   // 8192
    const int M = in_sizes[1] / D;   // 8192

    unsigned int* gmax = (unsigned int*)d_ws;

    init_gmax_kernel<<<1, 1, 0, stream>>>(gmax);
    dim3 grid(N / BM, M / BN);
    pairdist_max_kernel<<<grid, dim3(256), 0, stream>>>(L, R, gmax);
    finalize_kernel<<<1, 1, 0, stream>>>(gmax, (float*)d_out);
}

// Round 2
// 46.192 us; speedup vs baseline: 4.6290x; 4.6290x over previous
//
#include <hip/hip_runtime.h>
#include <hip/hip_bf16.h>
#include <math.h>

// max_{n,m} ||L[n]-R[m]||, L,R: [8192][64] fp32.
// Strategy: norms in exact fp32; cross term via bf16 MFMA (32x32x16).
// Error budget: bf16 rounding on the dot -> ~0.01 abs on final distance,
// threshold is 0.3425.

typedef __attribute__((ext_vector_type(8)))  short  short8;   // bf16x8 frag (4 VGPR)
typedef __attribute__((ext_vector_type(4)))  float  f32x4;
typedef __attribute__((ext_vector_type(16))) float  f32x16;   // 32x32 accum

constexpr int D  = 64;
constexpr int BM = 256;   // L rows per block
constexpr int BN = 128;   // R rows per block

__global__ void init_gmax_kernel(unsigned int* gmax) { *gmax = 0u; }

__device__ __forceinline__ short f2bf(float f) {
    __hip_bfloat16 h = __float2bfloat16(f);   // RNE, hw v_cvt
    return __builtin_bit_cast(short, h);
}

// 4 waves: wave grid 2(M) x 2(N); wave tile 128x64 = 4x2 subtiles of 32x32.
__global__ __launch_bounds__(256) void pairdist_mfma_kernel(
    const float* __restrict__ L, const float* __restrict__ R,
    unsigned int* __restrict__ gmax)
{
    // Frag-packed LDS: chunk [sub][kk][lane] = bf16x8 for
    //   row = sub*32 + (lane&31), k = kk*16 + (lane>>5)*8 + 0..7
    // -> every MFMA operand read is a lane-linear ds_read_b128 (conflict-free).
    __shared__ __align__(16) short A_pk[8][4][64][8];   // 32 KiB (256 rows)
    __shared__ __align__(16) short B_pk[4][4][64][8];   // 16 KiB (128 rows)
    __shared__ __align__(16) float lsq_s[BM];
    __shared__ __align__(16) float rsq_s[BN];
    __shared__ float wmax_s[4];

    const int tid = threadIdx.x;
    const int bm  = blockIdx.x * BM;
    const int bn  = blockIdx.y * BN;

    // ---- stage one L row per thread: fp32->bf16 packed + exact fp32 norm ----
    {
        const f32x4* src = reinterpret_cast<const f32x4*>(L + (size_t)(bm + tid) * D);
        const int ms = tid >> 5, li = tid & 31;
        float nrm = 0.f;
        #pragma unroll
        for (int kk = 0; kk < 4; ++kk) {
            #pragma unroll
            for (int kh = 0; kh < 2; ++kh) {
                f32x4 v0 = src[kk*4 + kh*2 + 0];
                f32x4 v1 = src[kk*4 + kh*2 + 1];
                short8 w;
                w[0]=f2bf(v0[0]); w[1]=f2bf(v0[1]); w[2]=f2bf(v0[2]); w[3]=f2bf(v0[3]);
                w[4]=f2bf(v1[0]); w[5]=f2bf(v1[1]); w[6]=f2bf(v1[2]); w[7]=f2bf(v1[3]);
                nrm = fmaf(v0[0],v0[0],nrm); nrm = fmaf(v0[1],v0[1],nrm);
                nrm = fmaf(v0[2],v0[2],nrm); nrm = fmaf(v0[3],v0[3],nrm);
                nrm = fmaf(v1[0],v1[0],nrm); nrm = fmaf(v1[1],v1[1],nrm);
                nrm = fmaf(v1[2],v1[2],nrm); nrm = fmaf(v1[3],v1[3],nrm);
                // two contiguous 512B sweeps per wave-instr -> conflict-free
                *reinterpret_cast<short8*>(&A_pk[ms][kk][kh*32 + li][0]) = w;
            }
        }
        lsq_s[tid] = nrm;
    }
    // ---- stage one R row for threads 0..127 ----
    if (tid < BN) {
        const f32x4* src = reinterpret_cast<const f32x4*>(R + (size_t)(bn + tid) * D);
        const int ns = tid >> 5, li = tid & 31;
        float nrm = 0.f;
        #pragma unroll
        for (int kk = 0; kk < 4; ++kk) {
            #pragma unroll
            for (int kh = 0; kh < 2; ++kh) {
                f32x4 v0 = src[kk*4 + kh*2 + 0];
                f32x4 v1 = src[kk*4 + kh*2 + 1];
                short8 w;
                w[0]=f2bf(v0[0]); w[1]=f2bf(v0[1]); w[2]=f2bf(v0[2]); w[3]=f2bf(v0[3]);
                w[4]=f2bf(v1[0]); w[5]=f2bf(v1[1]); w[6]=f2bf(v1[2]); w[7]=f2bf(v1[3]);
                nrm = fmaf(v0[0],v0[0],nrm); nrm = fmaf(v0[1],v0[1],nrm);
                nrm = fmaf(v0[2],v0[2],nrm); nrm = fmaf(v0[3],v0[3],nrm);
                nrm = fmaf(v1[0],v1[0],nrm); nrm = fmaf(v1[1],v1[1],nrm);
                nrm = fmaf(v1[2],v1[2],nrm); nrm = fmaf(v1[3],v1[3],nrm);
                *reinterpret_cast<short8*>(&B_pk[ns][kk][kh*32 + li][0]) = w;
            }
        }
        rsq_s[tid] = nrm;
    }
    __syncthreads();

    const int lane = tid & 63;
    const int wave = tid >> 6;
    const int wm = wave >> 1;      // 0..1 -> 128-row half of A tile
    const int wn = wave & 1;       // 0..1 -> 64-col half of B tile

    f32x16 acc[4][2] = {};
    #pragma unroll
    for (int kk = 0; kk < 4; ++kk) {
        short8 b0 = *reinterpret_cast<const short8*>(&B_pk[wn*2+0][kk][lane][0]);
        short8 b1 = *reinterpret_cast<const short8*>(&B_pk[wn*2+1][kk][lane][0]);
        #pragma unroll
        for (int ms = 0; ms < 4; ++ms) {
            short8 a = *reinterpret_cast<const short8*>(&A_pk[wm*4+ms][kk][lane][0]);
            acc[ms][0] = __builtin_amdgcn_mfma_f32_32x32x16_bf16(a, b0, acc[ms][0], 0, 0, 0);
            acc[ms][1] = __builtin_amdgcn_mfma_f32_32x32x16_bf16(a, b1, acc[ms][1], 0, 0, 0);
        }
    }

    // ---- epilogue: sq = lsq[row] + rsq[col] - 2*dot; running max ----
    // C layout (32x32, m74/m101): col = lane&31, row = (reg&3) + 8*(reg>>2) + 4*(lane>>5)
    const int col = lane & 31;
    const int h   = lane >> 5;
    const float rq0 = rsq_s[wn*64 +  0 + col];
    const float rq1 = rsq_s[wn*64 + 32 + col];
    float lmax = 0.f;
    #pragma unroll
    for (int ms = 0; ms < 4; ++ms) {
        const int rbase = wm*128 + ms*32 + 4*h;
        f32x4 lq0 = *reinterpret_cast<const f32x4*>(&lsq_s[rbase +  0]);
        f32x4 lq1 = *reinterpret_cast<const f32x4*>(&lsq_s[rbase +  8]);
        f32x4 lq2 = *reinterpret_cast<const f32x4*>(&lsq_s[rbase + 16]);
        f32x4 lq3 = *reinterpret_cast<const f32x4*>(&lsq_s[rbase + 24]);
        #pragma unroll
        for (int ns = 0; ns < 2; ++ns) {
            float m = -3.0e38f;
            #pragma unroll
            for (int g = 0; g < 4; ++g) {
                f32x4 lq = (g==0) ? lq0 : (g==1) ? lq1 : (g==2) ? lq2 : lq3;
                #pragma unroll
                for (int e = 0; e < 4; ++e) {
                    float a = acc[ms][ns][g*4 + e];
                    m = fmaxf(m, fmaf(-2.f, a, lq[e]));   // lsq - 2*dot
                }
            }
            lmax = fmaxf(lmax, m + (ns ? rq1 : rq0));     // + rsq (const per lane/subtile)
        }
    }

    #pragma unroll
    for (int off = 32; off >= 1; off >>= 1)
        lmax = fmaxf(lmax, __shfl_xor(lmax, off, 64));
    if (lane == 0) wmax_s[wave] = lmax;
    __syncthreads();
    if (tid == 0) {
        float bmax = fmaxf(fmaxf(wmax_s[0], wmax_s[1]), fmaxf(wmax_s[2], wmax_s[3]));
        bmax = fmaxf(bmax, 0.f);
        atomicMax(gmax, __float_as_uint(bmax));  // uint order == float order for >=0
    }
}

__global__ void finalize_kernel(const unsigned int* __restrict__ gmax,
                                float* __restrict__ out)
{
    out[0] = sqrtf(__uint_as_float(*gmax));
}

extern "C" void kernel_launch(void* const* d_in, const int* in_sizes, int n_in,
                              void* d_out, int out_size, void* d_ws, size_t ws_size,
                              hipStream_t stream) {
    const float* L = (const float*)d_in[0];
    const float* R = (const float*)d_in[1];
    const int N = in_sizes[0] / D;   // 8192
    const int M = in_sizes[1] / D;   // 8192

    unsigned int* gmax = (unsigned int*)d_ws;

    init_gmax_kernel<<<1, 1, 0, stream>>>(gmax);
    dim3 grid(N / BM, M / BN);
    pairdist_mfma_kernel<<<grid, dim3(256), 0, stream>>>(L, R, gmax);
    finalize_kernel<<<1, 1, 0, stream>>>(gmax, (float*)d_out);
}

// Round 3
// 39.770 us; speedup vs baseline: 5.3765x; 1.1615x over previous
//
#include <hip/hip_runtime.h>
#include <hip/hip_bf16.h>
#include <math.h>

// max_{n,m} ||L[n]-R[m]||, L,R: [8192][64] fp32.
// R3: prepack kernel converts fp32->bf16 ONCE into frag-packed layout in d_ws
// (+ exact fp32 row norms); main kernel stages via global_load_lds (16B) and
// runs the round-2-validated 32x32x16 bf16 MFMA tile + epilogue.

typedef __attribute__((ext_vector_type(8)))  short  short8;   // bf16x8 frag
typedef __attribute__((ext_vector_type(4)))  float  f32x4;
typedef __attribute__((ext_vector_type(16))) float  f32x16;   // 32x32 accum

constexpr int D  = 64;
constexpr int NR = 8192;  // rows per side
constexpr int BM = 256;
constexpr int BN = 128;

__device__ __forceinline__ short f2bf(float f) {
    __hip_bfloat16 h = __float2bfloat16(f);
    return __builtin_bit_cast(short, h);
}

// Frag-packed element index for row r, chunk kk (16 k's), k-half kh, elem e:
//   ((r>>5)*4 + kk)*512 + (kh*32 + (r&31))*8 + e     (shorts)
// A wave's ds_read_b128 at [chunk][kk][lane][0..7] is then lane-linear.

// ---- prepack: 4 threads per row, fully coalesced fp32 reads ----
__global__ __launch_bounds__(256) void prepack_kernel(
    const float* __restrict__ L, const float* __restrict__ R,
    short* __restrict__ Apk, short* __restrict__ Bpk,
    float* __restrict__ lsq, float* __restrict__ rsq,
    unsigned int* __restrict__ gmax)
{
    const int t = blockIdx.x * 256 + threadIdx.x;   // 0..65535
    const int r = t >> 2;                           // 0..16383
    const int j = t & 3;                            // kk chunk owned by this thread
    const bool isL = (r < NR);
    const int rr = isL ? r : r - NR;

    const float* src = (isL ? L : R) + (size_t)rr * D + j * 16;
    short* pk = isL ? Apk : Bpk;

    f32x4 v0 = *reinterpret_cast<const f32x4*>(src + 0);
    f32x4 v1 = *reinterpret_cast<const f32x4*>(src + 4);
    f32x4 v2 = *reinterpret_cast<const f32x4*>(src + 8);
    f32x4 v3 = *reinterpret_cast<const f32x4*>(src + 12);

    float p = 0.f;
    #pragma unroll
    for (int e = 0; e < 4; ++e) {
        p = fmaf(v0[e], v0[e], p); p = fmaf(v1[e], v1[e], p);
        p = fmaf(v2[e], v2[e], p); p = fmaf(v3[e], v3[e], p);
    }

    short8 w0, w1;
    #pragma unroll
    for (int e = 0; e < 4; ++e) {
        w0[e] = f2bf(v0[e]); w0[4+e] = f2bf(v1[e]);
        w1[e] = f2bf(v2[e]); w1[4+e] = f2bf(v3[e]);
    }
    const size_t base = ((size_t)(rr >> 5) * 4 + j) * 512;
    *reinterpret_cast<short8*>(pk + base + (0*32 + (rr & 31)) * 8) = w0;
    *reinterpret_cast<short8*>(pk + base + (1*32 + (rr & 31)) * 8) = w1;

    // row norm: sum 4 partials across the 4-thread group
    p += __shfl_xor(p, 1, 64);
    p += __shfl_xor(p, 2, 64);
    if (j == 0) (isL ? lsq : rsq)[rr] = p;

    if (t == 0) *gmax = 0u;
}

// ---- main: 4 waves, wave tile 128x64 (4x2 subtiles of 32x32x16) ----
__global__ __launch_bounds__(256) void pairdist_mfma_kernel(
    const short* __restrict__ Apk, const short* __restrict__ Bpk,
    const float* __restrict__ lsq, const float* __restrict__ rsq,
    unsigned int* __restrict__ gmax)
{
    __shared__ __align__(16) short A_lds[8][4][64][8];   // 32 KiB
    __shared__ __align__(16) short B_lds[4][4][64][8];   // 16 KiB
    __shared__ __align__(16) float lsq_s[BM];
    __shared__ __align__(16) float rsq_s[BN];
    __shared__ float wmax_s[4];

    const int tid  = threadIdx.x;
    const int lane = tid & 63;
    const int wave = tid >> 6;
    const int bm = blockIdx.x * BM;
    const int bn = blockIdx.y * BN;

    // Stage packed bf16 tiles: global layout == linear LDS layout, so
    // global_load_lds (wave-uniform LDS base + lane*16B) matches exactly.
    {
        const short* Ag = Apk + (size_t)(bm >> 5) * 2048;  // 8 groups * 2048 shorts
        short* Al = &A_lds[0][0][0][0];
        #pragma unroll
        for (int i = 0; i < 8; ++i) {
            const int soff = (i * 4 + wave) * 512;          // 1 KiB per wave-instr
            __builtin_amdgcn_global_load_lds(
                (const __attribute__((address_space(1))) unsigned int*)(Ag + soff + lane * 8),
                (__attribute__((address_space(3))) unsigned int*)(Al + soff),
                16, 0, 0);
        }
        const short* Bg = Bpk + (size_t)(bn >> 5) * 2048;
        short* Bl = &B_lds[0][0][0][0];
        #pragma unroll
        for (int i = 0; i < 4; ++i) {
            const int soff = (i * 4 + wave) * 512;
            __builtin_amdgcn_global_load_lds(
                (const __attribute__((address_space(1))) unsigned int*)(Bg + soff + lane * 8),
                (__attribute__((address_space(3))) unsigned int*)(Bl + soff),
                16, 0, 0);
        }
    }
    lsq_s[tid] = lsq[bm + tid];
    if (tid < BN) rsq_s[tid] = rsq[bn + tid];
    __syncthreads();   // compiler drains vmcnt+lgkmcnt here

    const int wm = wave >> 1;
    const int wn = wave & 1;

    f32x16 acc[4][2] = {};
    #pragma unroll
    for (int kk = 0; kk < 4; ++kk) {
        short8 b0 = *reinterpret_cast<const short8*>(&B_lds[wn*2+0][kk][lane][0]);
        short8 b1 = *reinterpret_cast<const short8*>(&B_lds[wn*2+1][kk][lane][0]);
        #pragma unroll
        for (int ms = 0; ms < 4; ++ms) {
            short8 a = *reinterpret_cast<const short8*>(&A_lds[wm*4+ms][kk][lane][0]);
            acc[ms][0] = __builtin_amdgcn_mfma_f32_32x32x16_bf16(a, b0, acc[ms][0], 0, 0, 0);
            acc[ms][1] = __builtin_amdgcn_mfma_f32_32x32x16_bf16(a, b1, acc[ms][1], 0, 0, 0);
        }
    }

    // epilogue: sq = lsq[row] + rsq[col] - 2*dot
    // C layout (32x32): col = lane&31, row = (reg&3) + 8*(reg>>2) + 4*(lane>>5)
    const int col = lane & 31;
    const int h   = lane >> 5;
    const float rq0 = rsq_s[wn*64 +  0 + col];
    const float rq1 = rsq_s[wn*64 + 32 + col];
    float lmax = 0.f;
    #pragma unroll
    for (int ms = 0; ms < 4; ++ms) {
        const int rbase = wm*128 + ms*32 + 4*h;
        f32x4 lq0 = *reinterpret_cast<const f32x4*>(&lsq_s[rbase +  0]);
        f32x4 lq1 = *reinterpret_cast<const f32x4*>(&lsq_s[rbase +  8]);
        f32x4 lq2 = *reinterpret_cast<const f32x4*>(&lsq_s[rbase + 16]);
        f32x4 lq3 = *reinterpret_cast<const f32x4*>(&lsq_s[rbase + 24]);
        #pragma unroll
        for (int ns = 0; ns < 2; ++ns) {
            float m = -3.0e38f;
            #pragma unroll
            for (int g = 0; g < 4; ++g) {
                f32x4 lq = (g==0) ? lq0 : (g==1) ? lq1 : (g==2) ? lq2 : lq3;
                #pragma unroll
                for (int e = 0; e < 4; ++e) {
                    float a = acc[ms][ns][g*4 + e];
                    m = fmaxf(m, fmaf(-2.f, a, lq[e]));
                }
            }
            lmax = fmaxf(lmax, m + (ns ? rq1 : rq0));
        }
    }

    #pragma unroll
    for (int off = 32; off >= 1; off >>= 1)
        lmax = fmaxf(lmax, __shfl_xor(lmax, off, 64));
    if (lane == 0) wmax_s[wave] = lmax;
    __syncthreads();
    if (tid == 0) {
        float bmax = fmaxf(fmaxf(wmax_s[0], wmax_s[1]), fmaxf(wmax_s[2], wmax_s[3]));
        bmax = fmaxf(bmax, 0.f);
        atomicMax(gmax, __float_as_uint(bmax));  // uint order == float order, >=0
    }
}

__global__ void finalize_kernel(const unsigned int* __restrict__ gmax,
                                float* __restrict__ out)
{
    out[0] = sqrtf(__uint_as_float(*gmax));
}

extern "C" void kernel_launch(void* const* d_in, const int* in_sizes, int n_in,
                              void* d_out, int out_size, void* d_ws, size_t ws_size,
                              hipStream_t stream) {
    const float* L = (const float*)d_in[0];
    const float* R = (const float*)d_in[1];

    unsigned int* gmax = (unsigned int*)d_ws;
    short* Apk = (short*)((char*)d_ws + 1024);
    short* Bpk = Apk + (size_t)NR * D;           // 524288 shorts each
    float* lsqg = (float*)(Bpk + (size_t)NR * D);
    float* rsqg = lsqg + NR;

    prepack_kernel<<<(2 * NR * 4) / 256, 256, 0, stream>>>(L, R, Apk, Bpk, lsqg, rsqg, gmax);
    dim3 grid(NR / BM, NR / BN);
    pairdist_mfma_kernel<<<grid, dim3(256), 0, stream>>>(Apk, Bpk, lsqg, rsqg, gmax);
    finalize_kernel<<<1, 1, 0, stream>>>(gmax, (float*)d_out);
}

// Round 4
// 28.755 us; speedup vs baseline: 7.4359x; 1.3830x over previous
//
#include <hip/hip_runtime.h>
#include <hip/hip_bf16.h>
#include <math.h>

// max_{n,m} ||L[n]-R[m]||, L,R: [8192][64] fp32.
// R4: no LDS in hot path. Prepack converts fp32->bf16 into frag-packed global
// layout (+ fp32 row norms). Main kernel loads MFMA fragments directly
// global->VGPR (coalesced 1KB dwordx4), keeps B-frags in registers across a
// 4-tile A loop, accumulates the max in registers, one atomic per block.

typedef __attribute__((ext_vector_type(8)))  short  short8;   // bf16x8 frag
typedef __attribute__((ext_vector_type(4)))  float  f32x4;
typedef __attribute__((ext_vector_type(16))) float  f32x16;   // 32x32 accum

constexpr int D  = 64;
constexpr int NR = 8192;

__device__ __forceinline__ short f2bf(float f) {
    __hip_bfloat16 h = __float2bfloat16(f);
    return __builtin_bit_cast(short, h);
}

// Frag-packed layout: for row r, k-chunk kk (16 k's), k-half kh, elem e:
//   short index = ((r>>5)*4 + kk)*512 + (kh*32 + (r&31))*8 + e
// A wave's frag load at [group][kk] + lane*8 is a contiguous 1KB dwordx4.

__global__ __launch_bounds__(256) void prepack_kernel(
    const float* __restrict__ L, const float* __restrict__ R,
    short* __restrict__ Apk, short* __restrict__ Bpk,
    float* __restrict__ lsq, float* __restrict__ rsq,
    unsigned int* __restrict__ outbits)
{
    const int t = blockIdx.x * 256 + threadIdx.x;   // 0..65535
    const int r = t >> 2;
    const int j = t & 3;                            // kk chunk
    const bool isL = (r < NR);
    const int rr = isL ? r : r - NR;

    const float* src = (isL ? L : R) + (size_t)rr * D + j * 16;
    short* pk = isL ? Apk : Bpk;

    f32x4 v0 = *reinterpret_cast<const f32x4*>(src + 0);
    f32x4 v1 = *reinterpret_cast<const f32x4*>(src + 4);
    f32x4 v2 = *reinterpret_cast<const f32x4*>(src + 8);
    f32x4 v3 = *reinterpret_cast<const f32x4*>(src + 12);

    float p = 0.f;
    #pragma unroll
    for (int e = 0; e < 4; ++e) {
        p = fmaf(v0[e], v0[e], p); p = fmaf(v1[e], v1[e], p);
        p = fmaf(v2[e], v2[e], p); p = fmaf(v3[e], v3[e], p);
    }

    short8 w0, w1;
    #pragma unroll
    for (int e = 0; e < 4; ++e) {
        w0[e] = f2bf(v0[e]); w0[4+e] = f2bf(v1[e]);
        w1[e] = f2bf(v2[e]); w1[4+e] = f2bf(v3[e]);
    }
    const size_t base = ((size_t)(rr >> 5) * 4 + j) * 512;
    *reinterpret_cast<short8*>(pk + base + (0*32 + (rr & 31)) * 8) = w0;
    *reinterpret_cast<short8*>(pk + base + (1*32 + (rr & 31)) * 8) = w1;

    p += __shfl_xor(p, 1, 64);
    p += __shfl_xor(p, 2, 64);
    if (j == 0) (isL ? lsq : rsq)[rr] = p;

    if (t == 0) *outbits = 0u;   // zero d_out (poisoned 0xAA by harness)
}

// Block: 4 waves, tile 128(m) x 256(n); wave = 128x64 (4x2 subtiles 32x32x16).
// Block loops over 4 A-tiles (owns 512 rows x 256 cols). B-frags in registers.
__global__ __launch_bounds__(256, 2) void pairdist_mfma_kernel(
    const short* __restrict__ Apk, const short* __restrict__ Bpk,
    const float* __restrict__ lsq, const float* __restrict__ rsq,
    unsigned int* __restrict__ outbits)
{
    __shared__ __align__(16) float lsq_s[512];
    __shared__ __align__(16) float rsq_s[256];
    __shared__ float wmax_s[4];

    const int tid  = threadIdx.x;
    const int lane = tid & 63;
    const int wave = tid >> 6;
    const int xc = blockIdx.x;     // 0..15  -> 512-row chunk of L
    const int yb = blockIdx.y;     // 0..31  -> 256-col chunk of R

    // stage norms (tiny LDS, no occupancy impact)
    lsq_s[tid]       = lsq[xc * 512 + tid];
    lsq_s[256 + tid] = lsq[xc * 512 + 256 + tid];
    rsq_s[tid]       = rsq[yb * 256 + tid];
    __syncthreads();

    // B-frags for this wave's 64 cols, all K: 8 x dwordx4, kept in VGPRs.
    const int cg = yb * 8 + wave * 2;            // 32-col group index
    short8 bf[2][4];
    #pragma unroll
    for (int ns = 0; ns < 2; ++ns)
        #pragma unroll
        for (int kk = 0; kk < 4; ++kk)
            bf[ns][kk] = *reinterpret_cast<const short8*>(
                Bpk + ((size_t)(cg + ns) * 4 + kk) * 512 + lane * 8);

    const int col = lane & 31;
    const int h   = lane >> 5;
    const float rq0 = rsq_s[wave * 64 +  0 + col];
    const float rq1 = rsq_s[wave * 64 + 32 + col];

    float lmax = 0.f;
    for (int t = 0; t < 4; ++t) {
        const int rg = xc * 16 + t * 4;          // 32-row group index
        // A-frags: same addresses for all 4 waves -> L1 broadcast.
        short8 af[4][4];
        #pragma unroll
        for (int ms = 0; ms < 4; ++ms)
            #pragma unroll
            for (int kk = 0; kk < 4; ++kk)
                af[ms][kk] = *reinterpret_cast<const short8*>(
                    Apk + ((size_t)(rg + ms) * 4 + kk) * 512 + lane * 8);

        f32x16 acc[4][2] = {};
        #pragma unroll
        for (int kk = 0; kk < 4; ++kk)
            #pragma unroll
            for (int ms = 0; ms < 4; ++ms) {
                acc[ms][0] = __builtin_amdgcn_mfma_f32_32x32x16_bf16(
                    af[ms][kk], bf[0][kk], acc[ms][0], 0, 0, 0);
                acc[ms][1] = __builtin_amdgcn_mfma_f32_32x32x16_bf16(
                    af[ms][kk], bf[1][kk], acc[ms][1], 0, 0, 0);
            }

        // epilogue: sq = lsq[row] + rsq[col] - 2*dot, folded into running max.
        // C layout (32x32): col = lane&31, row = (reg&3) + 8*(reg>>2) + 4*(lane>>5)
        #pragma unroll
        for (int ms = 0; ms < 4; ++ms) {
            const int rbase = t * 128 + ms * 32 + 4 * h;
            f32x4 lq0 = *reinterpret_cast<const f32x4*>(&lsq_s[rbase +  0]);
            f32x4 lq1 = *reinterpret_cast<const f32x4*>(&lsq_s[rbase +  8]);
            f32x4 lq2 = *reinterpret_cast<const f32x4*>(&lsq_s[rbase + 16]);
            f32x4 lq3 = *reinterpret_cast<const f32x4*>(&lsq_s[rbase + 24]);
            #pragma unroll
            for (int ns = 0; ns < 2; ++ns) {
                float m = -3.0e38f;
                #pragma unroll
                for (int g = 0; g < 4; ++g) {
                    f32x4 lq = (g==0) ? lq0 : (g==1) ? lq1 : (g==2) ? lq2 : lq3;
                    #pragma unroll
                    for (int e = 0; e < 4; ++e)
                        m = fmaxf(m, fmaf(-2.f, acc[ms][ns][g*4 + e], lq[e]));
                }
                lmax = fmaxf(lmax, m + (ns ? rq1 : rq0));
            }
        }
    }

    #pragma unroll
    for (int off = 32; off >= 1; off >>= 1)
        lmax = fmaxf(lmax, __shfl_xor(lmax, off, 64));
    if (lane == 0) wmax_s[wave] = lmax;
    __syncthreads();
    if (tid == 0) {
        float bmax = fmaxf(fmaxf(wmax_s[0], wmax_s[1]), fmaxf(wmax_s[2], wmax_s[3]));
        bmax = sqrtf(fmaxf(bmax, 0.f));          // sqrt monotone: max(sqrt)=sqrt(max)
        atomicMax(outbits, __float_as_uint(bmax)); // uint order == float order, >=0
    }
}

extern "C" void kernel_launch(void* const* d_in, const int* in_sizes, int n_in,
                              void* d_out, int out_size, void* d_ws, size_t ws_size,
                              hipStream_t stream) {
    const float* L = (const float*)d_in[0];
    const float* R = (const float*)d_in[1];

    short* Apk = (short*)((char*)d_ws + 1024);
    short* Bpk = Apk + (size_t)NR * D;
    float* lsqg = (float*)(Bpk + (size_t)NR * D);
    float* rsqg = lsqg + NR;
    unsigned int* outbits = (unsigned int*)d_out;

    prepack_kernel<<<(2 * NR * 4) / 256, 256, 0, stream>>>(L, R, Apk, Bpk, lsqg, rsqg, outbits);
    pairdist_mfma_kernel<<<dim3(16, 32), dim3(256), 0, stream>>>(Apk, Bpk, lsqg, rsqg, outbits);
}

// Round 5
// 23.926 us; speedup vs baseline: 8.9368x; 1.2018x over previous
//
#include <hip/hip_runtime.h>
#include <hip/hip_bf16.h>
#include <math.h>

// max_{n,m} ||L[n]-R[m]||, L,R: [8192][64] fp32.
// R5: prepack fp32->bf16 frag-packed global (+ fp32 norms). Main kernel:
// A staged via async global_load_lds (double-buffered, linear layout),
// B-frags in registers (wave grid 2x2 -> modest VGPR), 32x32x16 bf16 MFMA,
// epilogue folds lsq/rsq and a balanced max tree into a running register max.

typedef __attribute__((ext_vector_type(8)))  short  short8;   // bf16x8 frag
typedef __attribute__((ext_vector_type(4)))  float  f32x4;
typedef __attribute__((ext_vector_type(16))) float  f32x16;   // 32x32 accum

constexpr int D  = 64;
constexpr int NR = 8192;

__device__ __forceinline__ short f2bf(float f) {
    __hip_bfloat16 h = __float2bfloat16(f);
    return __builtin_bit_cast(short, h);
}

// Frag-packed layout: row r, k-chunk kk (16 k's), k-half kh, elem e:
//   short index = ((r>>5)*4 + kk)*512 + (kh*32 + (r&31))*8 + e
// -> a wave's frag access at [group][kk] + lane*8 is contiguous 1KB.

__global__ __launch_bounds__(256) void prepack_kernel(
    const float* __restrict__ L, const float* __restrict__ R,
    short* __restrict__ Apk, short* __restrict__ Bpk,
    float* __restrict__ lsq, float* __restrict__ rsq,
    unsigned int* __restrict__ outbits)
{
    const int t = blockIdx.x * 256 + threadIdx.x;   // 0..65535
    const int r = t >> 2;
    const int j = t & 3;                            // kk chunk
    const bool isL = (r < NR);
    const int rr = isL ? r : r - NR;

    const float* src = (isL ? L : R) + (size_t)rr * D + j * 16;
    short* pk = isL ? Apk : Bpk;

    f32x4 v0 = *reinterpret_cast<const f32x4*>(src + 0);
    f32x4 v1 = *reinterpret_cast<const f32x4*>(src + 4);
    f32x4 v2 = *reinterpret_cast<const f32x4*>(src + 8);
    f32x4 v3 = *reinterpret_cast<const f32x4*>(src + 12);

    float p = 0.f;
    #pragma unroll
    for (int e = 0; e < 4; ++e) {
        p = fmaf(v0[e], v0[e], p); p = fmaf(v1[e], v1[e], p);
        p = fmaf(v2[e], v2[e], p); p = fmaf(v3[e], v3[e], p);
    }

    short8 w0, w1;
    #pragma unroll
    for (int e = 0; e < 4; ++e) {
        w0[e] = f2bf(v0[e]); w0[4+e] = f2bf(v1[e]);
        w1[e] = f2bf(v2[e]); w1[4+e] = f2bf(v3[e]);
    }
    const size_t base = ((size_t)(rr >> 5) * 4 + j) * 512;
    *reinterpret_cast<short8*>(pk + base + (0*32 + (rr & 31)) * 8) = w0;
    *reinterpret_cast<short8*>(pk + base + (1*32 + (rr & 31)) * 8) = w1;

    p += __shfl_xor(p, 1, 64);
    p += __shfl_xor(p, 2, 64);
    if (j == 0) (isL ? lsq : rsq)[rr] = p;

    if (t == 0) *outbits = 0u;   // zero d_out (harness poisons 0xAA)
}

// Block: 4 waves (2x2 wave grid), tile 128(m) x 256(n); wave = 64x128
// (2x4 subtiles of 32x32x16). Block loops over 4 A-tiles (512 rows total).
// A double-buffered in LDS via global_load_lds; B-frags live in VGPRs.
__global__ __launch_bounds__(256, 2) void pairdist_mfma_kernel(
    const short* __restrict__ Apk, const short* __restrict__ Bpk,
    const float* __restrict__ lsq, const float* __restrict__ rsq,
    unsigned int* __restrict__ outbits)
{
    __shared__ __align__(16) short A_lds[2][4][4][64][8];  // 2 x 16 KiB
    __shared__ __align__(16) float lsq_s[512];
    __shared__ __align__(16) float rsq_s[256];
    __shared__ float wmax_s[4];

    const int tid  = threadIdx.x;
    const int lane = tid & 63;
    const int wave = tid >> 6;
    const int xc = blockIdx.x;     // 0..15 -> 512-row chunk of L
    const int yb = blockIdx.y;     // 0..31 -> 256-col chunk of R

    const size_t Abase = (size_t)(xc * 16) * 2048;   // shorts; +t*8192 per tile

    // stage tile 0 into buffer 0 (16 KB contiguous, 4 x 1KB per wave)
    {
        const short* At = Apk + Abase;
        short* dst = &A_lds[0][0][0][0][0];
        #pragma unroll
        for (int i = 0; i < 4; ++i) {
            const int off = (i * 4 + wave) * 512;
            __builtin_amdgcn_global_load_lds(
                (const __attribute__((address_space(1))) unsigned int*)(At + off + lane * 8),
                (__attribute__((address_space(3))) unsigned int*)(dst + off),
                16, 0, 0);
        }
    }

    lsq_s[tid]       = lsq[xc * 512 + tid];
    lsq_s[256 + tid] = lsq[xc * 512 + 256 + tid];
    rsq_s[tid]       = rsq[yb * 256 + tid];

    const int wm = wave >> 1;      // row half (64 rows) within 128-row tile
    const int wn = wave & 1;       // col half (128 cols) within 256
    // B-frags for this wave's 128 cols, all K: 16 x dwordx4 kept in VGPRs.
    short8 bf[4][4];
    #pragma unroll
    for (int nj = 0; nj < 4; ++nj)
        #pragma unroll
        for (int kk = 0; kk < 4; ++kk)
            bf[nj][kk] = *reinterpret_cast<const short8*>(
                Bpk + ((size_t)(yb * 8 + wn * 4 + nj) * 4 + kk) * 512 + lane * 8);

    __syncthreads();   // drains vmcnt: tile-0 stage complete

    const int col = lane & 31;
    const int h   = lane >> 5;
    float rq[4];
    #pragma unroll
    for (int nj = 0; nj < 4; ++nj) rq[nj] = rsq_s[wn * 128 + nj * 32 + col];

    float lmax = 0.f;
    int cur = 0;
    for (int t = 0; t < 4; ++t) {
        if (t < 3) {   // issue next-tile stage early; latency hides under MFMA
            const short* At = Apk + Abase + (size_t)(t + 1) * 8192;
            short* dst = &A_lds[cur ^ 1][0][0][0][0];
            #pragma unroll
            for (int i = 0; i < 4; ++i) {
                const int off = (i * 4 + wave) * 512;
                __builtin_amdgcn_global_load_lds(
                    (const __attribute__((address_space(1))) unsigned int*)(At + off + lane * 8),
                    (__attribute__((address_space(3))) unsigned int*)(dst + off),
                    16, 0, 0);
            }
        }

        f32x16 acc[2][4] = {};
        #pragma unroll
        for (int kk = 0; kk < 4; ++kk) {
            short8 a0 = *reinterpret_cast<const short8*>(&A_lds[cur][wm*2+0][kk][lane][0]);
            short8 a1 = *reinterpret_cast<const short8*>(&A_lds[cur][wm*2+1][kk][lane][0]);
            #pragma unroll
            for (int nj = 0; nj < 4; ++nj) {
                acc[0][nj] = __builtin_amdgcn_mfma_f32_32x32x16_bf16(a0, bf[nj][kk], acc[0][nj], 0, 0, 0);
                acc[1][nj] = __builtin_amdgcn_mfma_f32_32x32x16_bf16(a1, bf[nj][kk], acc[1][nj], 0, 0, 0);
            }
        }

        // epilogue: sq = lsq[row] + rsq[col] - 2*dot, balanced max tree.
        // C layout (32x32): col = lane&31, row = (reg&3) + 8*(reg>>2) + 4*(lane>>5)
        #pragma unroll
        for (int mi = 0; mi < 2; ++mi) {
            const int rbase = t * 128 + (wm * 2 + mi) * 32 + 4 * h;
            f32x4 lq[4];
            lq[0] = *reinterpret_cast<const f32x4*>(&lsq_s[rbase +  0]);
            lq[1] = *reinterpret_cast<const f32x4*>(&lsq_s[rbase +  8]);
            lq[2] = *reinterpret_cast<const f32x4*>(&lsq_s[rbase + 16]);
            lq[3] = *reinterpret_cast<const f32x4*>(&lsq_s[rbase + 24]);
            #pragma unroll
            for (int nj = 0; nj < 4; ++nj) {
                float x[16];
                #pragma unroll
                for (int g = 0; g < 4; ++g)
                    #pragma unroll
                    for (int e = 0; e < 4; ++e)
                        x[g*4+e] = fmaf(-2.f, acc[mi][nj][g*4+e], lq[g][e]);
                float y0 = fmaxf(x[0],  x[1]),  y1 = fmaxf(x[2],  x[3]);
                float y2 = fmaxf(x[4],  x[5]),  y3 = fmaxf(x[6],  x[7]);
                float y4 = fmaxf(x[8],  x[9]),  y5 = fmaxf(x[10], x[11]);
                float y6 = fmaxf(x[12], x[13]), y7 = fmaxf(x[14], x[15]);
                float z0 = fmaxf(y0, y1), z1 = fmaxf(y2, y3);
                float z2 = fmaxf(y4, y5), z3 = fmaxf(y6, y7);
                float m  = fmaxf(fmaxf(z0, z1), fmaxf(z2, z3));
                lmax = fmaxf(lmax, m + rq[nj]);
            }
        }

        __syncthreads();   // next-tile stage complete; safe to flip buffers
        cur ^= 1;
    }

    #pragma unroll
    for (int off = 32; off >= 1; off >>= 1)
        lmax = fmaxf(lmax, __shfl_xor(lmax, off, 64));
    if (lane == 0) wmax_s[wave] = lmax;
    __syncthreads();
    if (tid == 0) {
        float bmax = fmaxf(fmaxf(wmax_s[0], wmax_s[1]), fmaxf(wmax_s[2], wmax_s[3]));
        bmax = sqrtf(fmaxf(bmax, 0.f));            // sqrt monotone
        atomicMax(outbits, __float_as_uint(bmax)); // uint order == float order, >=0
    }
}

extern "C" void kernel_launch(void* const* d_in, const int* in_sizes, int n_in,
                              void* d_out, int out_size, void* d_ws, size_t ws_size,
                              hipStream_t stream) {
    const float* L = (const float*)d_in[0];
    const float* R = (const float*)d_in[1];

    short* Apk = (short*)d_ws;
    short* Bpk = Apk + (size_t)NR * D;           // 524288 shorts each
    float* lsqg = (float*)(Bpk + (size_t)NR * D);
    float* rsqg = lsqg + NR;
    unsigned int* outbits = (unsigned int*)d_out;

    prepack_kernel<<<(2 * NR * 4) / 256, 256, 0, stream>>>(L, R, Apk, Bpk, lsqg, rsqg, outbits);
    pairdist_mfma_kernel<<<dim3(16, 32), dim3(256), 0, stream>>>(Apk, Bpk, lsqg, rsqg, outbits);
}

// Round 6
// 21.866 us; speedup vs baseline: 9.7787x; 1.0942x over previous
//
#include <hip/hip_runtime.h>
#include <hip/hip_bf16.h>
#include <math.h>

// max_{n,m} ||L[n]-R[m]||, L,R: [8192][64] fp32.
// R6: prepack fp32->bf16 frag-packed (+ fp32 norms), 131072 threads.
// Main: block tile 128m x 256n, 4-tile m-loop; A double-buffered via
// global_load_lds; B split: nj=0,1 in registers, nj=2,3 in LDS (read per kk)
// -> peak regs ~190 (no spill risk). Per-block max -> slot store (no atomic
// contention); tiny finalize kernel reduces 512 slots + sqrt.

typedef __attribute__((ext_vector_type(8)))  short  short8;   // bf16x8 frag
typedef __attribute__((ext_vector_type(4)))  float  f32x4;
typedef __attribute__((ext_vector_type(16))) float  f32x16;   // 32x32 accum

constexpr int D  = 64;
constexpr int NR = 8192;
constexpr int NBLK = 16 * 32;   // main-kernel grid size

__device__ __forceinline__ short f2bf(float f) {
    __hip_bfloat16 h = __float2bfloat16(f);
    return __builtin_bit_cast(short, h);
}

// Frag-packed layout: row r, k-chunk kk (16 k's), k-half kh, elem e:
//   short index = ((r>>5)*4 + kk)*512 + (kh*32 + (r&31))*8 + e
// -> a wave's frag access at [group][kk] + lane*8 is contiguous 1KB.

// ---- prepack: 1 thread per (row, 8-float half-chunk); 8 threads/row ----
__global__ __launch_bounds__(256) void prepack_kernel(
    const float* __restrict__ L, const float* __restrict__ R,
    short* __restrict__ Apk, short* __restrict__ Bpk,
    float* __restrict__ lsq, float* __restrict__ rsq)
{
    const int t = blockIdx.x * 256 + threadIdx.x;   // 0..131071
    const int r = t >> 3;                           // 0..16383
    const int j = t & 7;                            // half-chunk
    const int kk = j >> 1, kh = j & 1;
    const bool isL = (r < NR);
    const int rr = isL ? r : r - NR;

    const float* src = (isL ? L : R) + (size_t)rr * D + j * 8;
    short* pk = isL ? Apk : Bpk;

    f32x4 v0 = *reinterpret_cast<const f32x4*>(src + 0);
    f32x4 v1 = *reinterpret_cast<const f32x4*>(src + 4);

    float p = 0.f;
    #pragma unroll
    for (int e = 0; e < 4; ++e) { p = fmaf(v0[e], v0[e], p); p = fmaf(v1[e], v1[e], p); }

    short8 w;
    #pragma unroll
    for (int e = 0; e < 4; ++e) { w[e] = f2bf(v0[e]); w[4+e] = f2bf(v1[e]); }
    *reinterpret_cast<short8*>(
        pk + ((size_t)(rr >> 5) * 4 + kk) * 512 + (kh * 32 + (rr & 31)) * 8) = w;

    // row norm across the 8-thread group (consecutive lanes)
    p += __shfl_xor(p, 1, 64);
    p += __shfl_xor(p, 2, 64);
    p += __shfl_xor(p, 4, 64);
    if (j == 0) (isL ? lsq : rsq)[rr] = p;
}

// ---- main: 4 waves (2x2), block 128m x 256n, wave 64m x 128n (2x4 subtiles).
// A: LDS dbuf (global_load_lds). B: nj=0,1 regs; nj=2,3 LDS read per kk.
__global__ __launch_bounds__(256, 2) void pairdist_mfma_kernel(
    const short* __restrict__ Apk, const short* __restrict__ Bpk,
    const float* __restrict__ lsq, const float* __restrict__ rsq,
    float* __restrict__ slots)
{
    __shared__ __align__(16) short A_lds[2][4][4][64][8];  // 2 x 16 KiB
    __shared__ __align__(16) short B_lds[4][4][64][8];     // 16 KiB (groups {2,3,6,7})
    __shared__ __align__(16) float lsq_s[512];
    __shared__ __align__(16) float rsq_s[256];
    __shared__ float wmax_s[4];

    const int tid  = threadIdx.x;
    const int lane = tid & 63;
    const int wave = tid >> 6;
    const int xc = blockIdx.x;     // 0..15 -> 512-row chunk of L
    const int yb = blockIdx.y;     // 0..31 -> 256-col chunk of R

    const size_t Abase = (size_t)(xc * 16) * 2048;   // shorts; +8192/tile

    // stage A tile 0 into buf 0: 16 x 1KB; wave handles kk=wave, i=0..3
    {
        const short* At = Apk + Abase;
        #pragma unroll
        for (int i = 0; i < 4; ++i)
            __builtin_amdgcn_global_load_lds(
                (const __attribute__((address_space(1))) unsigned int*)
                    (At + ((size_t)i * 4 + wave) * 512 + lane * 8),
                (__attribute__((address_space(3))) unsigned int*)
                    (&A_lds[0][i][wave][0][0]),
                16, 0, 0);
    }
    // stage B groups {2,3,6,7} (slots 0..3): wave handles kk=wave, s=0..3
    {
        #pragma unroll
        for (int s = 0; s < 4; ++s) {
            const int gsrc = yb * 8 + (s >> 1) * 4 + 2 + (s & 1);
            __builtin_amdgcn_global_load_lds(
                (const __attribute__((address_space(1))) unsigned int*)
                    (Bpk + ((size_t)gsrc * 4 + wave) * 512 + lane * 8),
                (__attribute__((address_space(3))) unsigned int*)
                    (&B_lds[s][wave][0][0]),
                16, 0, 0);
        }
    }

    lsq_s[tid]       = lsq[xc * 512 + tid];
    lsq_s[256 + tid] = lsq[xc * 512 + 256 + tid];
    rsq_s[tid]       = rsq[yb * 256 + tid];

    const int wm = wave >> 1;      // 64-row half of 128-row tile
    const int wn = wave & 1;       // 128-col half of 256
    // B-frags nj=0,1 in registers (8 x dwordx4)
    short8 bf[2][4];
    #pragma unroll
    for (int nj = 0; nj < 2; ++nj)
        #pragma unroll
        for (int kk = 0; kk < 4; ++kk)
            bf[nj][kk] = *reinterpret_cast<const short8*>(
                Bpk + ((size_t)(yb * 8 + wn * 4 + nj) * 4 + kk) * 512 + lane * 8);

    __syncthreads();   // drains vmcnt: A tile-0 + B staged

    const int col = lane & 31;
    const int h   = lane >> 5;
    float rq[4];
    #pragma unroll
    for (int nj = 0; nj < 4; ++nj) rq[nj] = rsq_s[wn * 128 + nj * 32 + col];

    float lmax = 0.f;
    int cur = 0;
    for (int t = 0; t < 4; ++t) {
        if (t < 3) {   // issue next A-tile stage; pin issue order
            const short* At = Apk + Abase + (size_t)(t + 1) * 8192;
            #pragma unroll
            for (int i = 0; i < 4; ++i)
                __builtin_amdgcn_global_load_lds(
                    (const __attribute__((address_space(1))) unsigned int*)
                        (At + ((size_t)i * 4 + wave) * 512 + lane * 8),
                    (__attribute__((address_space(3))) unsigned int*)
                        (&A_lds[cur ^ 1][i][wave][0][0]),
                    16, 0, 0);
            __builtin_amdgcn_sched_barrier(0);
        }

        f32x16 acc[2][4] = {};
        #pragma unroll
        for (int kk = 0; kk < 4; ++kk) {
            short8 a0 = *reinterpret_cast<const short8*>(&A_lds[cur][wm*2+0][kk][lane][0]);
            short8 a1 = *reinterpret_cast<const short8*>(&A_lds[cur][wm*2+1][kk][lane][0]);
            short8 b2 = *reinterpret_cast<const short8*>(&B_lds[wn*2+0][kk][lane][0]);
            short8 b3 = *reinterpret_cast<const short8*>(&B_lds[wn*2+1][kk][lane][0]);
            acc[0][0] = __builtin_amdgcn_mfma_f32_32x32x16_bf16(a0, bf[0][kk], acc[0][0], 0, 0, 0);
            acc[0][1] = __builtin_amdgcn_mfma_f32_32x32x16_bf16(a0, bf[1][kk], acc[0][1], 0, 0, 0);
            acc[0][2] = __builtin_amdgcn_mfma_f32_32x32x16_bf16(a0, b2,        acc[0][2], 0, 0, 0);
            acc[0][3] = __builtin_amdgcn_mfma_f32_32x32x16_bf16(a0, b3,        acc[0][3], 0, 0, 0);
            acc[1][0] = __builtin_amdgcn_mfma_f32_32x32x16_bf16(a1, bf[0][kk], acc[1][0], 0, 0, 0);
            acc[1][1] = __builtin_amdgcn_mfma_f32_32x32x16_bf16(a1, bf[1][kk], acc[1][1], 0, 0, 0);
            acc[1][2] = __builtin_amdgcn_mfma_f32_32x32x16_bf16(a1, b2,        acc[1][2], 0, 0, 0);
            acc[1][3] = __builtin_amdgcn_mfma_f32_32x32x16_bf16(a1, b3,        acc[1][3], 0, 0, 0);
        }

        // epilogue: sq = lsq[row] + rsq[col] - 2*dot, balanced max tree.
        // C layout (32x32): col = lane&31, row = (reg&3) + 8*(reg>>2) + 4*(lane>>5)
        #pragma unroll
        for (int mi = 0; mi < 2; ++mi) {
            const int rbase = t * 128 + (wm * 2 + mi) * 32 + 4 * h;
            f32x4 lq[4];
            lq[0] = *reinterpret_cast<const f32x4*>(&lsq_s[rbase +  0]);
            lq[1] = *reinterpret_cast<const f32x4*>(&lsq_s[rbase +  8]);
            lq[2] = *reinterpret_cast<const f32x4*>(&lsq_s[rbase + 16]);
            lq[3] = *reinterpret_cast<const f32x4*>(&lsq_s[rbase + 24]);
            #pragma unroll
            for (int nj = 0; nj < 4; ++nj) {
                float x[16];
                #pragma unroll
                for (int g = 0; g < 4; ++g)
                    #pragma unroll
                    for (int e = 0; e < 4; ++e)
                        x[g*4+e] = fmaf(-2.f, acc[mi][nj][g*4+e], lq[g][e]);
                float y0 = fmaxf(x[0],  x[1]),  y1 = fmaxf(x[2],  x[3]);
                float y2 = fmaxf(x[4],  x[5]),  y3 = fmaxf(x[6],  x[7]);
                float y4 = fmaxf(x[8],  x[9]),  y5 = fmaxf(x[10], x[11]);
                float y6 = fmaxf(x[12], x[13]), y7 = fmaxf(x[14], x[15]);
                float z0 = fmaxf(y0, y1), z1 = fmaxf(y2, y3);
                float z2 = fmaxf(y4, y5), z3 = fmaxf(y6, y7);
                float m  = fmaxf(fmaxf(z0, z1), fmaxf(z2, z3));
                lmax = fmaxf(lmax, m + rq[nj]);
            }
        }

        __syncthreads();   // next A-stage complete; safe to flip
        cur ^= 1;
    }

    #pragma unroll
    for (int off = 32; off >= 1; off >>= 1)
        lmax = fmaxf(lmax, __shfl_xor(lmax, off, 64));
    if (lane == 0) wmax_s[wave] = lmax;
    __syncthreads();
    if (tid == 0) {
        float bmax = fmaxf(fmaxf(wmax_s[0], wmax_s[1]), fmaxf(wmax_s[2], wmax_s[3]));
        slots[blockIdx.y * gridDim.x + blockIdx.x] = fmaxf(bmax, 0.f);  // plain store
    }
}

// ---- finalize: reduce 512 slots, sqrt, write scalar ----
__global__ __launch_bounds__(512) void finalize_kernel(
    const float* __restrict__ slots, float* __restrict__ out)
{
    __shared__ float wred[8];
    const int tid = threadIdx.x;
    float v = slots[tid];
    #pragma unroll
    for (int off = 32; off >= 1; off >>= 1)
        v = fmaxf(v, __shfl_xor(v, off, 64));
    if ((tid & 63) == 0) wred[tid >> 6] = v;
    __syncthreads();
    if (tid == 0) {
        float m = wred[0];
        #pragma unroll
        for (int i = 1; i < 8; ++i) m = fmaxf(m, wred[i]);
        out[0] = sqrtf(m);
    }
}

extern "C" void kernel_launch(void* const* d_in, const int* in_sizes, int n_in,
                              void* d_out, int out_size, void* d_ws, size_t ws_size,
                              hipStream_t stream) {
    const float* L = (const float*)d_in[0];
    const float* R = (const float*)d_in[1];

    short* Apk = (short*)d_ws;
    short* Bpk = Apk + (size_t)NR * D;           // 524288 shorts each
    float* lsqg = (float*)(Bpk + (size_t)NR * D);
    float* rsqg = lsqg + NR;
    float* slots = rsqg + NR;

    prepack_kernel<<<(2 * NR * 8) / 256, 256, 0, stream>>>(L, R, Apk, Bpk, lsqg, rsqg);
    pairdist_mfma_kernel<<<dim3(16, 32), dim3(256), 0, stream>>>(Apk, Bpk, lsqg, rsqg, slots);
    finalize_kernel<<<1, 512, 0, stream>>>(slots, (float*)d_out);
}